// Round 3
// baseline (388.585 us; speedup 1.0000x reference)
//
#include <hip/hip_runtime.h>
#include <hip/hip_bf16.h>

typedef __bf16 bf16;
typedef unsigned int u32;
typedef __attribute__((ext_vector_type(8))) __bf16 bf16x8;
typedef __attribute__((ext_vector_type(4))) float f32x4;

#define Bsz 256
#define Tsz 256
#define Csz 384
#define Hn  6
#define Dh  64
#define NQKV 1152   // 3 mats * 6 heads * 64

#define MFMA16(a, b, c) __builtin_amdgcn_mfma_f32_16x16x32_bf16(a, b, c, 0, 0, 0)

typedef __attribute__((address_space(3))) u32 lds_u32;
typedef __attribute__((address_space(1))) const u32 gbl_u32;
__device__ __forceinline__ void gl2lds16(const void* g, void* l) {
    // async global->LDS, 16B/lane; LDS dest = wave-uniform base + lane*16
    __builtin_amdgcn_global_load_lds((gbl_u32*)g, (lds_u32*)l, 16, 0, 0);
}

__device__ __forceinline__ float redmax16(float x) {
    x = fmaxf(x, __shfl_xor(x, 1));
    x = fmaxf(x, __shfl_xor(x, 2));
    x = fmaxf(x, __shfl_xor(x, 4));
    x = fmaxf(x, __shfl_xor(x, 8));
    return x;
}
__device__ __forceinline__ float redsum16(float x) {
    x += __shfl_xor(x, 1);
    x += __shfl_xor(x, 2);
    x += __shfl_xor(x, 4);
    x += __shfl_xor(x, 8);
    return x;
}

// ---------------- x: fp32 -> bf16 ----------------
__global__ __launch_bounds__(256) void convert_x(
    const float* __restrict__ x, bf16* __restrict__ xb)
{
    size_t i = ((size_t)blockIdx.x * 256 + threadIdx.x) * 8;
    float4 f0 = *(const float4*)&x[i];
    float4 f1 = *(const float4*)&x[i + 4];
    bf16x8 o;
    o[0] = (bf16)f0.x; o[1] = (bf16)f0.y; o[2] = (bf16)f0.z; o[3] = (bf16)f0.w;
    o[4] = (bf16)f1.x; o[5] = (bf16)f1.y; o[6] = (bf16)f1.z; o[7] = (bf16)f1.w;
    *(bf16x8*)&xb[i] = o;
}

// ---------------- weights: fp32 -> bf16, B^T [n][k] layout ----------------
__global__ __launch_bounds__(384) void prep_w(
    const float* __restrict__ Wq, const float* __restrict__ Wk,
    const float* __restrict__ Wv, const float* __restrict__ Wp,
    bf16* __restrict__ Btqkv, bf16* __restrict__ Bpt)
{
    const int n = blockIdx.x, k = threadIdx.x;
    if (n < NQKV) {
        int wi = n / Csz, rem = n - wi * Csz, h = rem >> 6, d = rem & 63;
        const float* W = wi == 0 ? Wq : (wi == 1 ? Wk : Wv);
        Btqkv[(size_t)n * Csz + k] = (bf16)W[((size_t)h * Csz + k) * Dh + d];
    } else {
        int n2 = n - NQKV;
        Bpt[(size_t)n2 * Csz + k] = (bf16)Wp[(size_t)k * Csz + n2];
    }
}

// ======================================================================
// Pipelined GEMM core v2: BM=256, BN=128, BK=64, 8 waves (512 thr),
// wave tile 64x64 (4M x 2N), ring-2 LDS (96 KiB -> 1 block/CU, 2 waves/SIMD),
// counted vmcnt (never 0 mid-loop), raw s_barrier, T2 XOR-swizzle
// (linear gl2lds dest + inverse-swizzled global source + swizzled ds_read),
// T5 setprio around the MFMA cluster. 2 waves/SIMD -> one wave's ds_read /
// stage phase overlaps the sibling wave's MFMA cluster.
// ======================================================================

__device__ __forceinline__ void stage_tile512(
    const char* Ab, const char* Bb, int m0, int n0, int t,
    char* AsB, char* BsB, int tid)
{
    const int srow = tid >> 3;                                   // 0..63
    const int scs  = ((tid & 7) * 16) ^ ((srow & 7) << 4);       // inv-swizzled col byte
    #pragma unroll
    for (int j = 0; j < 4; ++j)   // A: 256 rows x 128B
        gl2lds16(Ab + (size_t)(m0 + j * 64 + srow) * 768 + t * 128 + scs,
                 AsB + j * 8192 + tid * 16);
    #pragma unroll
    for (int j = 0; j < 2; ++j)   // B: 128 rows x 128B
        gl2lds16(Bb + (size_t)(n0 + j * 64 + srow) * 768 + t * 128 + scs,
                 BsB + j * 8192 + tid * 16);
}

__device__ __forceinline__ void compute_tile512(
    const char* Ap, const char* Bp,
    int wm4, int wn2, int l4, int quad, f32x4 acc[4][4])
{
    const int cswz = (l4 & 7) << 4;
    bf16x8 bfr[4][2], af[4][2];
    #pragma unroll
    for (int fn = 0; fn < 4; ++fn)
        #pragma unroll
        for (int ks = 0; ks < 2; ++ks)
            bfr[fn][ks] = *(const bf16x8*)(Bp + (wn2 * 64 + fn * 16 + l4) * 128 +
                                           ((ks * 64 + quad * 16) ^ cswz));
    #pragma unroll
    for (int fr = 0; fr < 4; ++fr)
        #pragma unroll
        for (int ks = 0; ks < 2; ++ks)
            af[fr][ks] = *(const bf16x8*)(Ap + (wm4 * 64 + fr * 16 + l4) * 128 +
                                          ((ks * 64 + quad * 16) ^ cswz));
    __builtin_amdgcn_s_setprio(1);
    #pragma unroll
    for (int ks = 0; ks < 2; ++ks)
        #pragma unroll
        for (int fr = 0; fr < 4; ++fr)
            #pragma unroll
            for (int fn = 0; fn < 4; ++fn)
                acc[fr][fn] = MFMA16(af[fr][ks], bfr[fn][ks], acc[fr][fn]);
    __builtin_amdgcn_s_setprio(0);
}

// ring-2: tile t lives in buf t%2; stage(t+1) issued before waiting on t.
// vmcnt(6): 12 outstanding (6 of tile t, 6 of t+1) -> wait until t's 6 landed.
#define GEMM_PIPE8()                                                           \
    stage_tile512(Ab, Bb, m0, n0, 0, As0, Bs0, tid);                           \
    _Pragma("unroll")                                                          \
    for (int t = 0; t < 6; ++t) {                                              \
        if (t < 5) stage_tile512(Ab, Bb, m0, n0, t + 1,                        \
                                 (t & 1) ? As0 : As1, (t & 1) ? Bs0 : Bs1, tid);\
        if (t < 5) { asm volatile("s_waitcnt vmcnt(6)" ::: "memory"); }        \
        else       { asm volatile("s_waitcnt vmcnt(0)" ::: "memory"); }        \
        __builtin_amdgcn_s_barrier();                                          \
        compute_tile512((t & 1) ? As1 : As0, (t & 1) ? Bs1 : Bs0,              \
                        wm4, wn2, l4, quad, acc);                              \
        __builtin_amdgcn_s_barrier();                                          \
    }

// ---------------- QKV: 65536x1152x384 ----------------
__global__ __launch_bounds__(512, 2) void qkv_gemm(
    const bf16* __restrict__ A, const bf16* __restrict__ Bt,
    bf16* __restrict__ q, bf16* __restrict__ k, bf16* __restrict__ v)
{
    __shared__ bf16 As[2][256][64];
    __shared__ bf16 Bs[2][128][64];
    char* As0 = (char*)&As[0][0][0]; char* As1 = (char*)&As[1][0][0];
    char* Bs0 = (char*)&Bs[0][0][0]; char* Bs1 = (char*)&Bs[1][0][0];
    const int tid = threadIdx.x, w = tid >> 6, lane = tid & 63;
    const int l4 = lane & 15, quad = lane >> 4;
    const int wm4 = w >> 1, wn2 = w & 1;

    // bijective XCD-chunk swizzle: nwg = 2304 = 8*288; n-tile fastest
    const int orig = blockIdx.x;
    const int id = (orig & 7) * 288 + (orig >> 3);
    const int mt_ = id / 9, nt_ = id - mt_ * 9;
    const int m0 = mt_ * 256, n0 = nt_ * 128;

    const char* Ab = (const char*)A;
    const char* Bb = (const char*)Bt;
    f32x4 acc[4][4] = {};

    GEMM_PIPE8();

    // epilogue: scatter n -> (wi,h,d); m -> (b,t)
    #pragma unroll
    for (int fn = 0; fn < 4; ++fn) {
        int n = n0 + wn2 * 64 + fn * 16 + l4;
        int wi = n / Csz, rem = n - wi * Csz;
        int h = rem >> 6, d = rem & 63;
        bf16* outp = wi == 0 ? q : (wi == 1 ? k : v);
        #pragma unroll
        for (int fr = 0; fr < 4; ++fr)
            #pragma unroll
            for (int r = 0; r < 4; ++r) {
                int m = m0 + wm4 * 64 + fr * 16 + quad * 4 + r;
                int b = m >> 8, tt = m & 255;
                outp[(((size_t)(b * Hn + h)) * Tsz + tt) * Dh + d] = (bf16)acc[fr][fn][r];
            }
    }
}

// ---------------- proj: 65536x384x384 ----------------
__global__ __launch_bounds__(512, 2) void proj_gemm(
    const bf16* __restrict__ A, const bf16* __restrict__ Bt,
    const float* __restrict__ bias, float* __restrict__ out)
{
    __shared__ bf16 As[2][256][64];
    __shared__ bf16 Bs[2][128][64];
    char* As0 = (char*)&As[0][0][0]; char* As1 = (char*)&As[1][0][0];
    char* Bs0 = (char*)&Bs[0][0][0]; char* Bs1 = (char*)&Bs[1][0][0];
    const int tid = threadIdx.x, w = tid >> 6, lane = tid & 63;
    const int l4 = lane & 15, quad = lane >> 4;
    const int wm4 = w >> 1, wn2 = w & 1;

    // nwg = 768 = 8*96; n-tile fastest
    const int orig = blockIdx.x;
    const int id = (orig & 7) * 96 + (orig >> 3);
    const int mt_ = id / 3, nt_ = id - mt_ * 3;
    const int m0 = mt_ * 256, n0 = nt_ * 128;

    const char* Ab = (const char*)A;
    const char* Bb = (const char*)Bt;
    f32x4 acc[4][4] = {};

    GEMM_PIPE8();

    #pragma unroll
    for (int fn = 0; fn < 4; ++fn) {
        int n = n0 + wn2 * 64 + fn * 16 + l4;
        float bv = bias[n];
        #pragma unroll
        for (int fr = 0; fr < 4; ++fr)
            #pragma unroll
            for (int r = 0; r < 4; ++r) {
                int m = m0 + wm4 * 64 + fr * 16 + quad * 4 + r;
                out[(size_t)m * Csz + n] = acc[fr][fn][r] + bv;
            }
    }
}

// ---------------- Flash attention, MFMA (exp2-domain softmax) ----------------
__global__ __launch_bounds__(256) void attn_mfma(
    const bf16* __restrict__ q, const bf16* __restrict__ k, const bf16* __restrict__ v,
    bf16* __restrict__ att)
{
    __shared__ bf16 Kl[64][72];
    __shared__ bf16 Vt[64][72];      // [d][s]
    __shared__ bf16 Pl[4][16][72];   // per-wave [qrow][s]
    const float SCL = 0.18033688f;   // 0.125 * log2(e)
    const int tid = threadIdx.x, w = tid >> 6, lane = tid & 63;
    const int l4 = lane & 15, quad = lane >> 4;

    // XCD-chunked swizzle (nblk = 6144 = 8 * 768)
    const int orig = blockIdx.x;
    const int blk = (orig & 7) * 768 + (orig >> 3);
    const int bh = blk >> 2, qt = blk & 3;
    const int b = bh / Hn, h = bh % Hn;
    const bf16* qb = q + (size_t)bh * Tsz * Dh;
    const bf16* kb = k + (size_t)bh * Tsz * Dh;
    const bf16* vb = v + (size_t)bh * Tsz * Dh;

    const int trow = qt * 64 + w * 16 + l4;
    const bf16x8 qa0 = *(const bf16x8*)&qb[trow * Dh + quad * 8];
    const bf16x8 qa1 = *(const bf16x8*)&qb[trow * Dh + 32 + quad * 8];

    f32x4 o[4] = {f32x4{0,0,0,0}, f32x4{0,0,0,0}, f32x4{0,0,0,0}, f32x4{0,0,0,0}};
    float mrun[4] = {-3.0e38f, -3.0e38f, -3.0e38f, -3.0e38f};
    float lrun[4] = {0.f, 0.f, 0.f, 0.f};

    for (int kt = 0; kt <= qt; ++kt) {
        #pragma unroll
        for (int it = 0; it < 2; ++it) {
            int idx = it * 256 + tid;
            int s = idx >> 3, d8 = (idx & 7) * 8;
            *(bf16x8*)&Kl[s][d8] = *(const bf16x8*)&kb[(kt * 64 + s) * Dh + d8];
        }
        #pragma unroll
        for (int it = 0; it < 2; ++it) {
            int idx = it * 256 + tid;
            int s = idx & 63, d8 = (idx >> 6) * 8;
            bf16x8 vv = *(const bf16x8*)&vb[(kt * 64 + s) * Dh + d8];
            #pragma unroll
            for (int j = 0; j < 8; ++j) Vt[d8 + j][s] = vv[j];
        }
        __syncthreads();

        f32x4 sc[4] = {f32x4{0,0,0,0}, f32x4{0,0,0,0}, f32x4{0,0,0,0}, f32x4{0,0,0,0}};
        #pragma unroll
        for (int nt = 0; nt < 4; ++nt) {
            bf16x8 b0 = *(const bf16x8*)&Kl[nt * 16 + l4][quad * 8];
            bf16x8 b1 = *(const bf16x8*)&Kl[nt * 16 + l4][32 + quad * 8];
            sc[nt] = MFMA16(qa0, b0, sc[nt]);
            sc[nt] = MFMA16(qa1, b1, sc[nt]);
        }

        float mnew[4], alpha[4];
        #pragma unroll
        for (int r = 0; r < 4; ++r) {
            int tg = qt * 64 + w * 16 + quad * 4 + r;
            float mx = mrun[r];
            #pragma unroll
            for (int nt = 0; nt < 4; ++nt) {
                float sv = sc[nt][r] * SCL;        // log2-domain
                int sg = kt * 64 + nt * 16 + l4;
                if (sg > tg) sv = -1.0e30f;
                sc[nt][r] = sv;
                mx = fmaxf(mx, sv);
            }
            mx = redmax16(mx);
            mnew[r] = mx;
            alpha[r] = __builtin_amdgcn_exp2f(mrun[r] - mx);
            mrun[r] = mx;
        }
        #pragma unroll
        for (int r = 0; r < 4; ++r) {
            float sm = 0.f;
            #pragma unroll
            for (int nt = 0; nt < 4; ++nt) {
                float e = __builtin_amdgcn_exp2f(sc[nt][r] - mnew[r]);
                sc[nt][r] = e;
                sm += e;
            }
            sm = redsum16(sm);
            lrun[r] = lrun[r] * alpha[r] + sm;
        }
        #pragma unroll
        for (int nt = 0; nt < 4; ++nt)
            #pragma unroll
            for (int r = 0; r < 4; ++r) o[nt][r] *= alpha[r];

        #pragma unroll
        for (int nt = 0; nt < 4; ++nt)
            #pragma unroll
            for (int r = 0; r < 4; ++r)
                Pl[w][quad * 4 + r][nt * 16 + l4] = (bf16)sc[nt][r];

        bf16x8 pa0 = *(const bf16x8*)&Pl[w][l4][quad * 8];
        bf16x8 pa1 = *(const bf16x8*)&Pl[w][l4][32 + quad * 8];
        #pragma unroll
        for (int nt = 0; nt < 4; ++nt) {
            bf16x8 vb0 = *(const bf16x8*)&Vt[nt * 16 + l4][quad * 8];
            bf16x8 vb1 = *(const bf16x8*)&Vt[nt * 16 + l4][32 + quad * 8];
            o[nt] = MFMA16(pa0, vb0, o[nt]);
            o[nt] = MFMA16(pa1, vb1, o[nt]);
        }
        __syncthreads();
    }

    #pragma unroll
    for (int r = 0; r < 4; ++r) {
        float inv = 1.f / lrun[r];
        int tg = qt * 64 + w * 16 + quad * 4 + r;
        #pragma unroll
        for (int nt = 0; nt < 4; ++nt)
            att[((size_t)(b * Tsz + tg)) * Csz + h * Dh + nt * 16 + l4] =
                (bf16)(o[nt][r] * inv);
    }
}

extern "C" void kernel_launch(void* const* d_in, const int* in_sizes, int n_in,
                              void* d_out, int out_size, void* d_ws, size_t ws_size,
                              hipStream_t stream)
{
    const float* x  = (const float*)d_in[0];
    const float* Wq = (const float*)d_in[1];
    const float* Wk = (const float*)d_in[2];
    const float* Wv = (const float*)d_in[3];
    const float* Wp = (const float*)d_in[4];
    const float* bp = (const float*)d_in[5];
    float* out = (float*)d_out;

    const size_t npe = (size_t)Bsz * Tsz * Csz;   // 25,165,824 elems
    bf16* xb    = (bf16*)d_ws;          // [65536,384]; reused as att after qkv
    bf16* att   = xb;                   // alias: xb dead once qkv_gemm completes
    bf16* q     = xb + npe;             // [B,H,T,D]
    bf16* k     = q  + npe;
    bf16* v     = k  + npe;
    bf16* Btqkv = v  + npe;             // [1152,384]
    bf16* Bpt   = Btqkv + (size_t)NQKV * Csz;   // [384,384]

    convert_x<<<npe / 2048, 256, 0, stream>>>(x, xb);
    prep_w<<<NQKV + Csz, 384, 0, stream>>>(Wq, Wk, Wv, Wp, Btqkv, Bpt);
    qkv_gemm<<<(Bsz * Tsz / 256) * (NQKV / 128), 512, 0, stream>>>(xb, Btqkv, q, k, v);
    attn_mfma<<<Bsz * Hn * 4, 256, 0, stream>>>(q, k, v, att);
    proj_gemm<<<(Bsz * Tsz / 256) * (Csz / 128), 512, 0, stream>>>(att, Bpt, bp, out);
}

// Round 4
// 369.589 us; speedup vs baseline: 1.0514x; 1.0514x over previous
//
#include <hip/hip_runtime.h>
#include <hip/hip_bf16.h>

typedef __bf16 bf16;
typedef unsigned int u32;
typedef __attribute__((ext_vector_type(8))) __bf16 bf16x8;
typedef __attribute__((ext_vector_type(4))) float f32x4;

#define Bsz 256
#define Tsz 256
#define Csz 384
#define Hn  6
#define Dh  64
#define NQKV 1152   // 3 mats * 6 heads * 64

#define MFMA16(a, b, c) __builtin_amdgcn_mfma_f32_16x16x32_bf16(a, b, c, 0, 0, 0)

typedef __attribute__((address_space(3))) u32 lds_u32;
typedef __attribute__((address_space(1))) const u32 gbl_u32;
__device__ __forceinline__ void gl2lds16(const void* g, void* l) {
    // async global->LDS, 16B/lane; LDS dest = wave-uniform base + lane*16
    __builtin_amdgcn_global_load_lds((gbl_u32*)g, (lds_u32*)l, 16, 0, 0);
}

__device__ __forceinline__ float redmax16(float x) {
    x = fmaxf(x, __shfl_xor(x, 1));
    x = fmaxf(x, __shfl_xor(x, 2));
    x = fmaxf(x, __shfl_xor(x, 4));
    x = fmaxf(x, __shfl_xor(x, 8));
    return x;
}
__device__ __forceinline__ float redsum16(float x) {
    x += __shfl_xor(x, 1);
    x += __shfl_xor(x, 2);
    x += __shfl_xor(x, 4);
    x += __shfl_xor(x, 8);
    return x;
}

// ---------------- x: fp32 -> bf16 ----------------
__global__ __launch_bounds__(256) void convert_x(
    const float* __restrict__ x, bf16* __restrict__ xb)
{
    size_t i = ((size_t)blockIdx.x * 256 + threadIdx.x) * 8;
    float4 f0 = *(const float4*)&x[i];
    float4 f1 = *(const float4*)&x[i + 4];
    bf16x8 o;
    o[0] = (bf16)f0.x; o[1] = (bf16)f0.y; o[2] = (bf16)f0.z; o[3] = (bf16)f0.w;
    o[4] = (bf16)f1.x; o[5] = (bf16)f1.y; o[6] = (bf16)f1.z; o[7] = (bf16)f1.w;
    *(bf16x8*)&xb[i] = o;
}

// ---------------- weights: fp32 -> bf16, B^T [n][k] layout ----------------
__global__ __launch_bounds__(384) void prep_w(
    const float* __restrict__ Wq, const float* __restrict__ Wk,
    const float* __restrict__ Wv, const float* __restrict__ Wp,
    bf16* __restrict__ Btqkv, bf16* __restrict__ Bpt)
{
    const int n = blockIdx.x, k = threadIdx.x;
    if (n < NQKV) {
        int wi = n / Csz, rem = n - wi * Csz, h = rem >> 6, d = rem & 63;
        const float* W = wi == 0 ? Wq : (wi == 1 ? Wk : Wv);
        Btqkv[(size_t)n * Csz + k] = (bf16)W[((size_t)h * Csz + k) * Dh + d];
    } else {
        int n2 = n - NQKV;
        Bpt[(size_t)n2 * Csz + k] = (bf16)Wp[(size_t)k * Csz + n2];
    }
}

// ======================================================================
// Pipelined GEMM core v2: BM=256, BN=128, BK=64, 8 waves (512 thr),
// wave tile 64x64 (4M x 2N), ring-2 LDS (96 KiB -> 1 block/CU, 2 waves/SIMD),
// counted vmcnt (never 0 mid-loop), raw s_barrier, T2 XOR-swizzle.
// ======================================================================

__device__ __forceinline__ void stage_tile512(
    const char* Ab, const char* Bb, int m0, int n0, int t,
    char* AsB, char* BsB, int tid)
{
    const int srow = tid >> 3;                                   // 0..63
    const int scs  = ((tid & 7) * 16) ^ ((srow & 7) << 4);       // inv-swizzled col byte
    #pragma unroll
    for (int j = 0; j < 4; ++j)   // A: 256 rows x 128B
        gl2lds16(Ab + (size_t)(m0 + j * 64 + srow) * 768 + t * 128 + scs,
                 AsB + j * 8192 + tid * 16);
    #pragma unroll
    for (int j = 0; j < 2; ++j)   // B: 128 rows x 128B
        gl2lds16(Bb + (size_t)(n0 + j * 64 + srow) * 768 + t * 128 + scs,
                 BsB + j * 8192 + tid * 16);
}

__device__ __forceinline__ void compute_tile512(
    const char* Ap, const char* Bp,
    int wm4, int wn2, int l4, int quad, f32x4 acc[4][4])
{
    const int cswz = (l4 & 7) << 4;
    bf16x8 bfr[4][2], af[4][2];
    #pragma unroll
    for (int fn = 0; fn < 4; ++fn)
        #pragma unroll
        for (int ks = 0; ks < 2; ++ks)
            bfr[fn][ks] = *(const bf16x8*)(Bp + (wn2 * 64 + fn * 16 + l4) * 128 +
                                           ((ks * 64 + quad * 16) ^ cswz));
    #pragma unroll
    for (int fr = 0; fr < 4; ++fr)
        #pragma unroll
        for (int ks = 0; ks < 2; ++ks)
            af[fr][ks] = *(const bf16x8*)(Ap + (wm4 * 64 + fr * 16 + l4) * 128 +
                                          ((ks * 64 + quad * 16) ^ cswz));
    __builtin_amdgcn_s_setprio(1);
    #pragma unroll
    for (int ks = 0; ks < 2; ++ks)
        #pragma unroll
        for (int fr = 0; fr < 4; ++fr)
            #pragma unroll
            for (int fn = 0; fn < 4; ++fn)
                acc[fr][fn] = MFMA16(af[fr][ks], bfr[fn][ks], acc[fr][fn]);
    __builtin_amdgcn_s_setprio(0);
}

// ring-2: tile t lives in buf t%2; stage(t+1) issued before waiting on t.
#define GEMM_PIPE8()                                                           \
    stage_tile512(Ab, Bb, m0, n0, 0, As0, Bs0, tid);                           \
    _Pragma("unroll")                                                          \
    for (int t = 0; t < 6; ++t) {                                              \
        if (t < 5) stage_tile512(Ab, Bb, m0, n0, t + 1,                        \
                                 (t & 1) ? As0 : As1, (t & 1) ? Bs0 : Bs1, tid);\
        if (t < 5) { asm volatile("s_waitcnt vmcnt(6)" ::: "memory"); }        \
        else       { asm volatile("s_waitcnt vmcnt(0)" ::: "memory"); }        \
        __builtin_amdgcn_s_barrier();                                          \
        compute_tile512((t & 1) ? As1 : As0, (t & 1) ? Bs1 : Bs0,              \
                        wm4, wn2, l4, quad, acc);                              \
        __builtin_amdgcn_s_barrier();                                          \
    }

// ---------------- QKV: 65536x1152x384 ----------------
__global__ __launch_bounds__(512, 2) void qkv_gemm(
    const bf16* __restrict__ A, const bf16* __restrict__ Bt,
    bf16* __restrict__ q, bf16* __restrict__ k, bf16* __restrict__ v)
{
    __shared__ bf16 As[2][256][64];
    __shared__ bf16 Bs[2][128][64];
    char* As0 = (char*)&As[0][0][0]; char* As1 = (char*)&As[1][0][0];
    char* Bs0 = (char*)&Bs[0][0][0]; char* Bs1 = (char*)&Bs[1][0][0];
    const int tid = threadIdx.x, w = tid >> 6, lane = tid & 63;
    const int l4 = lane & 15, quad = lane >> 4;
    const int wm4 = w >> 1, wn2 = w & 1;

    // bijective XCD-chunk swizzle: nwg = 2304 = 8*288; n-tile fastest
    const int orig = blockIdx.x;
    const int id = (orig & 7) * 288 + (orig >> 3);
    const int mt_ = id / 9, nt_ = id - mt_ * 9;
    const int m0 = mt_ * 256, n0 = nt_ * 128;

    const char* Ab = (const char*)A;
    const char* Bb = (const char*)Bt;
    f32x4 acc[4][4] = {};

    GEMM_PIPE8();

    // epilogue: scatter n -> (wi,h,d); m -> (b,t)
    #pragma unroll
    for (int fn = 0; fn < 4; ++fn) {
        int n = n0 + wn2 * 64 + fn * 16 + l4;
        int wi = n / Csz, rem = n - wi * Csz;
        int h = rem >> 6, d = rem & 63;
        bf16* outp = wi == 0 ? q : (wi == 1 ? k : v);
        #pragma unroll
        for (int fr = 0; fr < 4; ++fr)
            #pragma unroll
            for (int r = 0; r < 4; ++r) {
                int m = m0 + wm4 * 64 + fr * 16 + quad * 4 + r;
                int b = m >> 8, tt = m & 255;
                outp[(((size_t)(b * Hn + h)) * Tsz + tt) * Dh + d] = (bf16)acc[fr][fn][r];
            }
    }
}

// ---------------- proj: 65536x384x384 ----------------
__global__ __launch_bounds__(512, 2) void proj_gemm(
    const bf16* __restrict__ A, const bf16* __restrict__ Bt,
    const float* __restrict__ bias, float* __restrict__ out)
{
    __shared__ bf16 As[2][256][64];
    __shared__ bf16 Bs[2][128][64];
    char* As0 = (char*)&As[0][0][0]; char* As1 = (char*)&As[1][0][0];
    char* Bs0 = (char*)&Bs[0][0][0]; char* Bs1 = (char*)&Bs[1][0][0];
    const int tid = threadIdx.x, w = tid >> 6, lane = tid & 63;
    const int l4 = lane & 15, quad = lane >> 4;
    const int wm4 = w >> 1, wn2 = w & 1;

    // nwg = 768 = 8*96; n-tile fastest
    const int orig = blockIdx.x;
    const int id = (orig & 7) * 96 + (orig >> 3);
    const int mt_ = id / 3, nt_ = id - mt_ * 3;
    const int m0 = mt_ * 256, n0 = nt_ * 128;

    const char* Ab = (const char*)A;
    const char* Bb = (const char*)Bt;
    f32x4 acc[4][4] = {};

    GEMM_PIPE8();

    #pragma unroll
    for (int fn = 0; fn < 4; ++fn) {
        int n = n0 + wn2 * 64 + fn * 16 + l4;
        float bv = bias[n];
        #pragma unroll
        for (int fr = 0; fr < 4; ++fr)
            #pragma unroll
            for (int r = 0; r < 4; ++r) {
                int m = m0 + wm4 * 64 + fr * 16 + quad * 4 + r;
                out[(size_t)m * Csz + n] = acc[fr][fn][r] + bv;
            }
    }
}

// ======================================================================
// Flash attention v2: one block per (b,h), 512 threads (8 waves).
// K (256x64) + V^T (64x256) staged in LDS ONCE, single barrier, then a
// barrier-free main loop: wave w owns Q fragments {w, 15-w} (16 rows each)
// -> every wave does exactly 5 causal kt-tiles (perfect balance).
// Desynced waves: one wave's softmax shuffle-chain overlaps the sibling
// wave's MFMA (T5 setprio arbitrates). All LDS XOR-swizzled (chunk^row&7,
// the R2-GEMM measured-zero pattern): 32+32+16 = 80 KiB -> 2 blocks/CU.
// ======================================================================
__global__ __launch_bounds__(512, 4) void attn_mfma(
    const bf16* __restrict__ q, const bf16* __restrict__ k, const bf16* __restrict__ v,
    bf16* __restrict__ att)
{
    __shared__ bf16 Kl[256][64];     // [s][d], swizzled
    __shared__ bf16 Vt[64][256];     // [d][s], swizzled
    __shared__ bf16 Pl[8][16][64];   // per-wave [qrow][s_local], swizzled
    const float SCL = 0.18033688f;   // 0.125 * log2(e)
    const int tid = threadIdx.x, w = tid >> 6, lane = tid & 63;
    const int l4 = lane & 15, quad = lane >> 4;
    const int cswz = l4 & 7;         // row&7 == l4&7 for all fragment reads
    const int bh = blockIdx.x;
    const int b = bh / Hn, h = bh % Hn;
    const bf16* qb = q + (size_t)bh * Tsz * Dh;
    const bf16* kb = k + (size_t)bh * Tsz * Dh;
    const bf16* vb = v + (size_t)bh * Tsz * Dh;
    char* KlB = (char*)&Kl[0][0];
    char* VtB = (char*)&Vt[0][0];
    char* PlB = (char*)&Pl[w][0][0];

    // Q for both fragments up-front (L3-hit; latency hides under staging)
    bf16x8 qa[2][2];
    #pragma unroll
    for (int fi = 0; fi < 2; ++fi) {
        int g = fi ? 15 - w : w;
        qa[fi][0] = *(const bf16x8*)&qb[(g * 16 + l4) * Dh + quad * 8];
        qa[fi][1] = *(const bf16x8*)&qb[(g * 16 + l4) * Dh + 32 + quad * 8];
    }

    // ---- stage K: linear global read, swizzled LDS write
    #pragma unroll
    for (int it = 0; it < 4; ++it) {
        int c = it * 512 + tid;                  // 16B chunk, 2048 total
        int row = c >> 3, ck = c & 7;
        bf16x8 kv = *(const bf16x8*)((const char*)kb + (size_t)c * 16);
        *(bf16x8*)(KlB + row * 128 + ((ck ^ (row & 7)) << 4)) = kv;
    }
    // ---- stage V transposed: Vt[d][s], swizzled
    #pragma unroll
    for (int it = 0; it < 4; ++it) {
        int idx = it * 512 + tid;
        int s = idx & 63, g2 = idx >> 6;         // g2 0..31
        int d8 = (g2 & 7) * 8, sg = (g2 >> 3) * 64 + s;
        bf16x8 vv = *(const bf16x8*)&vb[(size_t)sg * Dh + d8];
        #pragma unroll
        for (int j = 0; j < 8; ++j) {
            int row = d8 + j;
            *(bf16*)(VtB + row * 512 + (((sg >> 3) ^ (row & 7)) << 4) + (sg & 7) * 2) = vv[j];
        }
    }
    __syncthreads();

    #pragma unroll
    for (int fi = 0; fi < 2; ++fi) {
        const int g = fi ? 15 - w : w;
        const int diag = g >> 2;
        const int tg = g * 16 + quad * 4;        // +r = output row
        f32x4 o[4] = {f32x4{0,0,0,0}, f32x4{0,0,0,0}, f32x4{0,0,0,0}, f32x4{0,0,0,0}};
        float mrun[4] = {-3.0e38f, -3.0e38f, -3.0e38f, -3.0e38f};
        float lrun[4] = {0.f, 0.f, 0.f, 0.f};

        for (int kt = 0; kt <= diag; ++kt) {
            // ---- QK^T
            f32x4 sc[4] = {f32x4{0,0,0,0}, f32x4{0,0,0,0}, f32x4{0,0,0,0}, f32x4{0,0,0,0}};
            __builtin_amdgcn_s_setprio(1);
            #pragma unroll
            for (int nt = 0; nt < 4; ++nt) {
                const char* kbase = KlB + (kt * 64 + nt * 16 + l4) * 128;
                bf16x8 b0 = *(const bf16x8*)(kbase + ((quad ^ cswz) << 4));
                bf16x8 b1 = *(const bf16x8*)(kbase + (((4 + quad) ^ cswz) << 4));
                sc[nt] = MFMA16(qa[fi][0], b0, sc[nt]);
                sc[nt] = MFMA16(qa[fi][1], b1, sc[nt]);
            }
            __builtin_amdgcn_s_setprio(0);

            // ---- online softmax (mask only on diagonal tile)
            const bool isdiag = (kt == diag);
            float mnew[4], alpha[4];
            #pragma unroll
            for (int r = 0; r < 4; ++r) {
                float mx = mrun[r];
                #pragma unroll
                for (int nt = 0; nt < 4; ++nt) {
                    float sv = sc[nt][r] * SCL;  // log2-domain
                    if (isdiag) {
                        int sg2 = kt * 64 + nt * 16 + l4;
                        if (sg2 > tg + r) sv = -1.0e30f;
                    }
                    sc[nt][r] = sv;
                    mx = fmaxf(mx, sv);
                }
                mx = redmax16(mx);
                mnew[r] = mx;
                alpha[r] = __builtin_amdgcn_exp2f(mrun[r] - mx);
                mrun[r] = mx;
            }
            #pragma unroll
            for (int r = 0; r < 4; ++r) {
                float sm = 0.f;
                #pragma unroll
                for (int nt = 0; nt < 4; ++nt) {
                    float e = __builtin_amdgcn_exp2f(sc[nt][r] - mnew[r]);
                    sc[nt][r] = e;
                    sm += e;
                }
                sm = redsum16(sm);
                lrun[r] = lrun[r] * alpha[r] + sm;
            }
            #pragma unroll
            for (int nt = 0; nt < 4; ++nt)
                #pragma unroll
                for (int r = 0; r < 4; ++r) o[nt][r] *= alpha[r];

            // ---- P -> LDS (per-wave, swizzled)
            #pragma unroll
            for (int nt = 0; nt < 4; ++nt)
                #pragma unroll
                for (int r = 0; r < 4; ++r) {
                    int row = quad * 4 + r;
                    int colc = nt * 2 + (l4 >> 3);
                    *(bf16*)(PlB + row * 128 + ((colc ^ (row & 7)) << 4) + (l4 & 7) * 2)
                        = (bf16)sc[nt][r];
                }
            bf16x8 pa0 = *(const bf16x8*)(PlB + l4 * 128 + ((quad ^ cswz) << 4));
            bf16x8 pa1 = *(const bf16x8*)(PlB + l4 * 128 + (((4 + quad) ^ cswz) << 4));

            // ---- PV
            __builtin_amdgcn_s_setprio(1);
            #pragma unroll
            for (int nt = 0; nt < 4; ++nt) {
                const char* vbase = VtB + (nt * 16 + l4) * 512;
                bf16x8 v0 = *(const bf16x8*)(vbase + (((kt * 8 + quad) ^ cswz) << 4));
                bf16x8 v1 = *(const bf16x8*)(vbase + (((kt * 8 + 4 + quad) ^ cswz) << 4));
                o[nt] = MFMA16(pa0, v0, o[nt]);
                o[nt] = MFMA16(pa1, v1, o[nt]);
            }
            __builtin_amdgcn_s_setprio(0);
        }

        // ---- fragment epilogue
        #pragma unroll
        for (int r = 0; r < 4; ++r) {
            float inv = 1.f / lrun[r];
            #pragma unroll
            for (int nt = 0; nt < 4; ++nt)
                att[((size_t)(b * Tsz + tg + r)) * Csz + h * Dh + nt * 16 + l4] =
                    (bf16)(o[nt][r] * inv);
        }
    }
}

extern "C" void kernel_launch(void* const* d_in, const int* in_sizes, int n_in,
                              void* d_out, int out_size, void* d_ws, size_t ws_size,
                              hipStream_t stream)
{
    const float* x  = (const float*)d_in[0];
    const float* Wq = (const float*)d_in[1];
    const float* Wk = (const float*)d_in[2];
    const float* Wv = (const float*)d_in[3];
    const float* Wp = (const float*)d_in[4];
    const float* bp = (const float*)d_in[5];
    float* out = (float*)d_out;

    const size_t npe = (size_t)Bsz * Tsz * Csz;   // 25,165,824 elems
    bf16* xb    = (bf16*)d_ws;          // [65536,384]; reused as att after qkv
    bf16* att   = xb;                   // alias: xb dead once qkv_gemm completes
    bf16* q     = xb + npe;             // [B,H,T,D]
    bf16* k     = q  + npe;
    bf16* v     = k  + npe;
    bf16* Btqkv = v  + npe;             // [1152,384]
    bf16* Bpt   = Btqkv + (size_t)NQKV * Csz;   // [384,384]

    convert_x<<<npe / 2048, 256, 0, stream>>>(x, xb);
    prep_w<<<NQKV + Csz, 384, 0, stream>>>(Wq, Wk, Wv, Wp, Btqkv, Bpt);
    qkv_gemm<<<(Bsz * Tsz / 256) * (NQKV / 128), 512, 0, stream>>>(xb, Btqkv, q, k, v);
    attn_mfma<<<Bsz * Hn, 512, 0, stream>>>(q, k, v, att);
    proj_gemm<<<(Bsz * Tsz / 256) * (Csz / 128), 512, 0, stream>>>(att, Bpt, bp, out);
}